// Round 2
// baseline (2182.510 us; speedup 1.0000x reference)
//
#include <hip/hip_runtime.h>
#include <stdint.h>

typedef unsigned short u16;
typedef unsigned int   u32;
typedef short  s8v  __attribute__((ext_vector_type(8)));
typedef __bf16 bf8v __attribute__((ext_vector_type(8)));
typedef float  f4v  __attribute__((ext_vector_type(4)));
typedef u16    u16x4 __attribute__((ext_vector_type(4)));
typedef u16    u16x8 __attribute__((ext_vector_type(8)));

#define NTOK   16384
#define HD     512
#define FD     2048
#define NE     8
#define MAXROWS 33792      // segments padded to 128 rows: 32768 + 8*127 <= 33792
#define MAXTASK 544        // <= 2*sum(ceil(cnt_e/128)) worst case 528
#define FCH    32
#define NCHH   32          // chunks per task = (FD/2)/FCH

// ws layout (bytes); total need = 51380224
// ctrl ints: [0..7] counts, [8..15] fill, [16..23] segoff, [24] rows, [25] tasks, [26] steal,
//            [64..64+MAXTASK) task map (1 int: e | fh<<3 | i<<4)
#define CTRL_OFF   0
#define TOKE_OFF   8192       // int[NTOK]
#define COMB_OFF   73728      // float[NTOK*8]
#define LIST_OFF   598016     // int[MAXROWS]   (135168 B)
#define ROWW_OFF   733184     // float[MAXROWS] (135168 B, ends 868352 < XBF_OFF)
#define XBF_OFF    1048576    // u16 [NTOK][HD]        bf16 copy of x
#define W1T_OFF    17825792   // u16 [NE][FD][HD]      bf16, transposed
#define W2T_OFF    34603008   // u16 [NE][HD][FD]      bf16, transposed
#define WS_NEED    51380224ull

__device__ __forceinline__ u16 f2bf(float f) {
    union { float f; u32 u; } v; v.f = f;
    u32 r = v.u + 0x7FFFu + ((v.u >> 16) & 1u);
    return (u16)(r >> 16);
}
__device__ __forceinline__ float gelu_f(float v) {
    float u = 0.7978845608028654f * (v + 0.044715f * v * v * v);
    float t = 1.f - 2.f / (__expf(2.f * u) + 1.f);
    return 0.5f * v * (1.f + t);
}

// mfma wrapper: ROCm versions differ on whether the builtin takes v8i16 or v8bf16.
template <typename V>
__device__ __forceinline__ auto mfma_try(V a, V b, f4v c, int)
    -> decltype(__builtin_amdgcn_mfma_f32_16x16x32_bf16(a, b, c, 0, 0, 0)) {
    return __builtin_amdgcn_mfma_f32_16x16x32_bf16(a, b, c, 0, 0, 0);
}
template <typename V>
__device__ __forceinline__ f4v mfma_try(V a, V b, f4v c, long) {
    return __builtin_amdgcn_mfma_f32_16x16x32_bf16(
        __builtin_bit_cast(bf8v, a), __builtin_bit_cast(bf8v, b), c, 0, 0, 0);
}
__device__ __forceinline__ f4v mfma16(s8v a, s8v b, f4v c) { return mfma_try(a, b, c, 0); }

// ---------------- diagnostic fallback ----------------
__global__ __launch_bounds__(256) void k_fallback(float* __restrict__ out) {
    int i = (blockIdx.x * 256 + threadIdx.x) * 4;
    *(f4v*)(out + i) = (f4v){0.f, 0.f, 0.f, 0.f};
}

// ---------------- zero per-call state ----------------
__global__ __launch_bounds__(256) void k_zero(int* __restrict__ ctrl, int* __restrict__ list,
                                              float* __restrict__ roww, float* __restrict__ out) {
    int id = blockIdx.x * 256 + threadIdx.x;
    *(f4v*)(out + (size_t)id * 4) = (f4v){0.f, 0.f, 0.f, 0.f};
    if (id < MAXROWS) { list[id] = 0; roww[id] = 0.f; }
    if (id < 64) ctrl[id] = 0;
}

// ---------------- transpose+cast (vectorized): f32 [R][C] -> bf16 [C][R] per expert ----------------
__global__ __launch_bounds__(256) void k_transpose(const float* __restrict__ in, u16* __restrict__ out,
                                                   int R, int C) {
    __shared__ float tile[64][65];
    size_t base = (size_t)blockIdx.z * R * C;
    const float* ip = in + base;
    u16* op = out + base;
    int c0 = blockIdx.x * 64, r0 = blockIdx.y * 64;
#pragma unroll
    for (int i = 0; i < 4; i++) {
        int idx = threadIdx.x + i * 256;
        int r = idx >> 4, c4 = (idx & 15) * 4;
        f4v v = *(const f4v*)(ip + (size_t)(r0 + r) * C + c0 + c4);
#pragma unroll
        for (int j = 0; j < 4; j++) tile[r][c4 + j] = v[j];
    }
    __syncthreads();
#pragma unroll
    for (int i = 0; i < 4; i++) {
        int idx = threadIdx.x + i * 256;
        int c = idx >> 4, r4 = (idx & 15) * 4;
        u16x4 o;
#pragma unroll
        for (int j = 0; j < 4; j++) o[j] = f2bf(tile[r4 + j][c]);
        *(u16x4*)(op + (size_t)(c0 + c) * R + r0 + r4) = o;
    }
}

// ---------------- gating (f32): softmax + top2, one wave/token; writes bf16 x copy; NO atomics ----------------
__global__ __launch_bounds__(256) void k_gate(const float* __restrict__ x, const float* __restrict__ Wg,
                                              const float* __restrict__ bg, float* __restrict__ comb,
                                              int* __restrict__ toke, u16* __restrict__ xbf) {
    int lane = threadIdx.x & 63;
    int t = (blockIdx.x * 4 + (threadIdx.x >> 6)) & (NTOK - 1);
    const float* xr = x + (size_t)t * HD;
    f4v xa = *(const f4v*)(xr + lane * 8);
    f4v xb = *(const f4v*)(xr + lane * 8 + 4);
    u16x8 o;
#pragma unroll
    for (int j = 0; j < 4; j++) { o[j] = f2bf(xa[j]); o[4 + j] = f2bf(xb[j]); }
    *(u16x8*)(xbf + (size_t)t * HD + lane * 8) = o;

    float p[8];
#pragma unroll
    for (int e = 0; e < 8; e++) p[e] = 0.f;
#pragma unroll
    for (int j = 0; j < 4; j++) {
        int h0 = lane * 8 + j, h1 = lane * 8 + 4 + j;
        f4v wa0 = *(const f4v*)(Wg + h0 * 8);
        f4v wa1 = *(const f4v*)(Wg + h0 * 8 + 4);
        f4v wb0 = *(const f4v*)(Wg + h1 * 8);
        f4v wb1 = *(const f4v*)(Wg + h1 * 8 + 4);
#pragma unroll
        for (int e = 0; e < 4; e++) {
            p[e]     += xa[j] * wa0[e] + xb[j] * wb0[e];
            p[4 + e] += xa[j] * wa1[e] + xb[j] * wb1[e];
        }
    }
#pragma unroll
    for (int off = 32; off > 0; off >>= 1)
#pragma unroll
        for (int e = 0; e < 8; e++) p[e] += __shfl_xor(p[e], off, 64);
#pragma unroll
    for (int e = 0; e < 8; e++) p[e] += bg[e];
    float mx = p[0];
#pragma unroll
    for (int e = 1; e < 8; e++) mx = fmaxf(mx, p[e]);
    float pr[8]; float s = 0.f;
#pragma unroll
    for (int e = 0; e < 8; e++) { pr[e] = __expf(p[e] - mx); s += pr[e]; }
    float inv = 1.f / s;
#pragma unroll
    for (int e = 0; e < 8; e++) pr[e] *= inv;
    int i1 = 0; float v1 = pr[0];
#pragma unroll
    for (int e = 1; e < 8; e++) if (pr[e] > v1) { v1 = pr[e]; i1 = e; }
    int i2 = 0; float v2 = -1.f;
#pragma unroll
    for (int e = 0; e < 8; e++) if (e != i1 && pr[e] > v2) { v2 = pr[e]; i2 = e; }
    if (lane == 0) {
#pragma unroll
        for (int e = 0; e < 8; e++) comb[t * 8 + e] = (e == i1 || e == i2) ? pr[e] : 0.f;
        toke[t] = i1 | (i2 << 8);
    }
}

// ---------------- counts via LDS aggregation ----------------
__global__ __launch_bounds__(1024) void k_count(const int* __restrict__ toke, int* __restrict__ ctrl) {
    __shared__ int sCnt[8];
    if (threadIdx.x < 8) sCnt[threadIdx.x] = 0;
    __syncthreads();
    int t = blockIdx.x * 1024 + threadIdx.x;
    int te = toke[t];
    atomicAdd(&sCnt[te & 7], 1);
    atomicAdd(&sCnt[(te >> 8) & 7], 1);
    __syncthreads();
    if (threadIdx.x < 8) atomicAdd(&ctrl[threadIdx.x], sCnt[threadIdx.x]);
}

// ---------------- plan: 128-row segments, tasks = (mtile, fhalf), e-major order ----------------
__global__ __launch_bounds__(640) void k_plan(int* __restrict__ ctrl) {
    __shared__ int sOff[9], sNT[8];
    if (threadIdx.x == 0) {
        int seg = 0, tt = 0;
        for (int e = 0; e < 8; e++) {
            ctrl[16 + e] = seg;
            sOff[e] = tt;
            int nt = (ctrl[e] + 127) >> 7;
            sNT[e] = nt;
            tt += 2 * nt;
            seg += nt * 128;
        }
        sOff[8] = tt;
        ctrl[24] = seg;
        ctrl[25] = (tt < MAXTASK) ? tt : MAXTASK;
    }
    __syncthreads();
    int ntask = sOff[8] < MAXTASK ? sOff[8] : MAXTASK;
    for (int t = threadIdx.x; t < ntask; t += 640) {
        int e = 0;
        while (e < 7 && t >= sOff[e + 1]) e++;
        int local = t - sOff[e];
        int nt = sNT[e];
        int fh = (local >= nt) ? 1 : 0;
        int i = local - fh * nt;
        ctrl[64 + t] = e | (fh << 3) | (i << 4);
    }
}

// ---------------- scatter with LDS rank aggregation ----------------
__global__ __launch_bounds__(1024) void k_scatter(const int* __restrict__ toke, const float* __restrict__ comb,
                                                  int* __restrict__ ctrl, int* __restrict__ list,
                                                  float* __restrict__ roww) {
    __shared__ int sCnt[8], sBase[8];
    if (threadIdx.x < 8) sCnt[threadIdx.x] = 0;
    __syncthreads();
    int t = blockIdx.x * 1024 + threadIdx.x;
    int te = toke[t];
    int e1 = te & 7, e2 = (te >> 8) & 7;
    int r1 = atomicAdd(&sCnt[e1], 1);
    int r2 = atomicAdd(&sCnt[e2], 1);
    __syncthreads();
    if (threadIdx.x < 8) sBase[threadIdx.x] = atomicAdd(&ctrl[8 + threadIdx.x], sCnt[threadIdx.x]);
    __syncthreads();
    int g1 = min(ctrl[16 + e1] + sBase[e1] + r1, MAXROWS - 1);
    list[g1] = t; roww[g1] = comb[t * 8 + e1];
    int g2 = min(ctrl[16 + e2] + sBase[e2] + r2, MAXROWS - 1);
    list[g2] = t; roww[g2] = comb[t * 8 + e2];
}

// ---------------- fused expert FFN v4: 128-row x F/2 tasks, A in regs, global steal ----------------
// 2x weight-traffic cut vs v2/v3: each 2 MB weight slice amortized over 128 rows.
// 8 waves: phase1 wave = m-block (16 rows, fb=0..1 frags); phase2 wave = 64-wide n-slice, 8 m-blocks.
__global__ __launch_bounds__(512, 4) void k_main(const u16* __restrict__ xbf, const float* __restrict__ b1g,
                                                 const float* __restrict__ b2g, const u16* __restrict__ W1T,
                                                 const u16* __restrict__ W2T, const int* __restrict__ ctrl,
                                                 int* __restrict__ steal, const int* __restrict__ list,
                                                 const float* __restrict__ roww, float* __restrict__ out) {
    __shared__ u16 sW1[32 * 512];   // XOR-swizzled: phys8 = (c&~7)|((c&7)^(f&7))
    __shared__ u16 sW2[512 * 32];   // 16B-granule XOR: chunk' = chunk ^ ((n>>2)&3)
    __shared__ u16 sH[128 * 40];    // pad to 40 els: 2-way banks on b128 reads
    __shared__ int sTile;
    const int tid = threadIdx.x, wave = tid >> 6, lane = tid & 63;
    const int quad = lane >> 4, l15 = lane & 15;
    const int total = min(ctrl[25], MAXTASK);

    for (;;) {
        if (tid == 0) sTile = atomicAdd(steal, 1);
        __syncthreads();
        int bt = sTile;
        if (bt >= total) break;
        int mword = ctrl[64 + bt];
        int e  = mword & 7;
        int fh = (mword >> 3) & 1;
        int it = mword >> 4;
        int row0   = min(ctrl[16 + e] + it * 128, MAXROWS - 128);
        int inseg0 = it * 128;
        int cnt    = ctrl[e];
        const u16* w1e = W1T + (size_t)e * FD * HD + (size_t)fh * 1024 * HD;  // [f][h], f-slice
        const u16* w2e = W2T + (size_t)e * HD * FD + fh * 1024;               // [n][f], f-slice
        const float* b1e = b1g + e * FD + fh * 1024;

        // ---- preload A fragments (this wave's 16 rows) into registers, reused all 32 chunks ----
        int mA = wave * 16 + l15;
        int tokA = (inseg0 + mA < cnt) ? (list[row0 + mA] & (NTOK - 1)) : 0;
        const u16* xrow = xbf + (size_t)tokA * HD + quad * 8;
        s8v A[16];
#pragma unroll
        for (int ks = 0; ks < 16; ks++) A[ks] = *(const s8v*)(xrow + ks * 32);

        f4v Y[8][4];
#pragma unroll
        for (int mb = 0; mb < 8; mb++)
#pragma unroll
            for (int nb = 0; nb < 4; nb++) Y[mb][nb] = (f4v){0.f, 0.f, 0.f, 0.f};

        for (int c = 0; c < NCHH; c++) {
            __syncthreads();   // all waves done with prev chunk's sW1/sW2/sH
            // ---- stage: sW1 (32x512 swizzled) + sW2 (512x32, 16B-granule swizzle) ----
#pragma unroll
            for (int t8 = 0; t8 < 4; t8++) {
                int u = t8 * 512 + tid;
                int f = u >> 6, cu = u & 63;
                int phys = (cu & ~7) | ((cu & 7) ^ (f & 7));
                u16x8 v = *(const u16x8*)(w1e + (size_t)(c * FCH + f) * HD + cu * 8);
                *(u16x8*)(sW1 + f * 512 + phys * 8) = v;
            }
#pragma unroll
            for (int t8 = 0; t8 < 4; t8++) {
                int u = t8 * 512 + tid;
                int n = u >> 2, cu = u & 3;
                u16x8 v = *(const u16x8*)(w2e + (size_t)n * FD + c * FCH + cu * 8);
                *(u16x8*)(sW2 + n * 32 + ((cu ^ ((n >> 2) & 3)) * 8)) = v;
            }
            __syncthreads();   // staging visible
            // ---- phase 1: H[128][32] for this chunk; wave = m-block, 2 f-frags ----
#pragma unroll
            for (int fb = 0; fb < 2; fb++) {
                int fs = fb * 16 + l15;
                f4v h = (f4v){0.f, 0.f, 0.f, 0.f};
#pragma unroll
                for (int ks = 0; ks < 16; ks++) {
                    int cidx = ks * 4 + quad;
                    int phys = (cidx & ~7) | ((cidx & 7) ^ (fs & 7));
                    s8v b = *(const s8v*)(sW1 + fs * 512 + phys * 8);
                    h = mfma16(A[ks], b, h);
                }
                float bb = b1e[c * FCH + fs];
#pragma unroll
                for (int r = 0; r < 4; r++)
                    sH[(wave * 16 + quad * 4 + r) * 40 + fs] = f2bf(gelu_f(h[r] + bb));
            }
            __syncthreads();   // sH visible
            // ---- phase 2: Y += H_chunk @ W2_chunk; wave covers n in [wave*64, wave*64+64) ----
            s8v aH[8];
#pragma unroll
            for (int mb = 0; mb < 8; mb++)
                aH[mb] = *(const s8v*)(sH + (mb * 16 + l15) * 40 + quad * 8);
#pragma unroll
            for (int nb = 0; nb < 4; nb++) {
                int n = wave * 64 + nb * 16 + l15;
                s8v bw = *(const s8v*)(sW2 + n * 32 + ((quad ^ ((n >> 2) & 3)) * 8));
#pragma unroll
                for (int mb = 0; mb < 8; mb++) Y[mb][nb] = mfma16(aH[mb], bw, Y[mb][nb]);
            }
        }
        // ---- epilogue: (Y + b2[fh==0 only]) * routing weight, atomic accumulate ----
        float b2v[4];
#pragma unroll
        for (int nb = 0; nb < 4; nb++)
            b2v[nb] = fh ? 0.f : b2g[e * HD + wave * 64 + nb * 16 + l15];
#pragma unroll
        for (int mb = 0; mb < 8; mb++) {
#pragma unroll
            for (int r = 0; r < 4; r++) {
                int m = mb * 16 + quad * 4 + r;
                bool val = (inseg0 + m) < cnt;
                int tok = list[row0 + m] & (NTOK - 1);
                float wgt = val ? roww[row0 + m] : 0.f;
                float* orow = out + (size_t)tok * HD + wave * 64 + l15;
#pragma unroll
                for (int nb = 0; nb < 4; nb++)
                    atomicAdd(orow + nb * 16, (Y[mb][nb][r] + b2v[nb]) * wgt);
            }
        }
    }
}

extern "C" void kernel_launch(void* const* d_in, const int* in_sizes, int n_in,
                              void* d_out, int out_size, void* d_ws, size_t ws_size,
                              hipStream_t stream) {
    const float* x  = (const float*)d_in[0];
    const float* Wg = (const float*)d_in[1];
    const float* bg = (const float*)d_in[2];
    const float* W1 = (const float*)d_in[3];
    const float* b1 = (const float*)d_in[4];
    const float* W2 = (const float*)d_in[5];
    const float* b2 = (const float*)d_in[6];
    (void)in_sizes; (void)n_in; (void)out_size;
    float* out = (float*)d_out;

    if (ws_size < WS_NEED) {
        k_fallback<<<(NTOK * HD / 4) / 256, 256, 0, stream>>>(out);
        return;
    }

    char* ws = (char*)d_ws;
    int*   ctrl = (int*)(ws + CTRL_OFF);
    int*   toke = (int*)(ws + TOKE_OFF);
    float* comb = (float*)(ws + COMB_OFF);
    int*   list = (int*)(ws + LIST_OFF);
    float* roww = (float*)(ws + ROWW_OFF);
    u16*   xbf  = (u16*)(ws + XBF_OFF);
    u16*   w1t  = (u16*)(ws + W1T_OFF);
    u16*   w2t  = (u16*)(ws + W2T_OFF);

    k_zero<<<(NTOK * HD / 4) / 256, 256, 0, stream>>>(ctrl, list, roww, out);
    k_transpose<<<dim3(FD / 64, HD / 64, NE), dim3(256), 0, stream>>>(W1, w1t, HD, FD);
    k_transpose<<<dim3(HD / 64, FD / 64, NE), dim3(256), 0, stream>>>(W2, w2t, FD, HD);
    k_gate<<<NTOK / 4, 256, 0, stream>>>(x, Wg, bg, comb, toke, xbf);
    k_count<<<NTOK / 1024, 1024, 0, stream>>>(toke, ctrl);
    k_plan<<<1, 640, 0, stream>>>(ctrl);
    k_scatter<<<NTOK / 1024, 1024, 0, stream>>>(toke, comb, ctrl, list, roww);
    k_main<<<512, 512, 0, stream>>>(xbf, b1, b2, w1t, w2t, ctrl, ctrl + 26, list, roww, out);
}

// Round 3
// 916.537 us; speedup vs baseline: 2.3813x; 2.3813x over previous
//
#include <hip/hip_runtime.h>
#include <stdint.h>

typedef unsigned short u16;
typedef unsigned int   u32;
typedef short  s8v  __attribute__((ext_vector_type(8)));
typedef __bf16 bf8v __attribute__((ext_vector_type(8)));
typedef float  f4v  __attribute__((ext_vector_type(4)));
typedef u16    u16x4 __attribute__((ext_vector_type(4)));
typedef u16    u16x8 __attribute__((ext_vector_type(8)));

#define NTOK   16384
#define HD     512
#define FD     2048
#define NE     8
#define MAXROWS 33280
#define MAXTILES 520
#define FCH    32
#define NCH    64   // FD / FCH

// ws layout (bytes); total need = 51380224
#define CTRL_OFF   0          // ints: [0..7] counts, [8..15] fill, [16..23] segoff, [24] rows, [25] tiles, [26] steal, [32..] map
#define TOKE_OFF   8192       // int[NTOK]
#define COMB_OFF   73728      // float[NTOK*8]
#define LIST_OFF   598016     // int[MAXROWS]
#define ROWW_OFF   731136     // float[MAXROWS]
#define XBF_OFF    1048576    // u16 [NTOK][HD]        bf16 copy of x
#define W1T_OFF    17825792   // u16 [NE][FD][HD]      bf16, transposed
#define W2T_OFF    34603008   // u16 [NE][HD][FD]      bf16, transposed
#define WS_NEED    51380224ull

__device__ __forceinline__ u16 f2bf(float f) {
    union { float f; u32 u; } v; v.f = f;
    u32 r = v.u + 0x7FFFu + ((v.u >> 16) & 1u);
    return (u16)(r >> 16);
}
__device__ __forceinline__ float gelu_f(float v) {
    float u = 0.7978845608028654f * (v + 0.044715f * v * v * v);
    float t = 1.f - 2.f / (__expf(2.f * u) + 1.f);
    return 0.5f * v * (1.f + t);
}

// mfma wrapper: ROCm versions differ on whether the builtin takes v8i16 or v8bf16.
template <typename V>
__device__ __forceinline__ auto mfma_try(V a, V b, f4v c, int)
    -> decltype(__builtin_amdgcn_mfma_f32_16x16x32_bf16(a, b, c, 0, 0, 0)) {
    return __builtin_amdgcn_mfma_f32_16x16x32_bf16(a, b, c, 0, 0, 0);
}
template <typename V>
__device__ __forceinline__ f4v mfma_try(V a, V b, f4v c, long) {
    return __builtin_amdgcn_mfma_f32_16x16x32_bf16(
        __builtin_bit_cast(bf8v, a), __builtin_bit_cast(bf8v, b), c, 0, 0, 0);
}
__device__ __forceinline__ f4v mfma16(s8v a, s8v b, f4v c) { return mfma_try(a, b, c, 0); }

// async global->LDS, 16B per lane; lds base must be wave-uniform (HW adds lane*16)
__device__ __forceinline__ void gload16(const u16* g, u16* l) {
    __builtin_amdgcn_global_load_lds(
        (const __attribute__((address_space(1))) unsigned int*)g,
        (__attribute__((address_space(3))) unsigned int*)l, 16, 0, 0);
}

// ---------------- diagnostic fallback ----------------
__global__ __launch_bounds__(256) void k_fallback(float* __restrict__ out) {
    int i = (blockIdx.x * 256 + threadIdx.x) * 4;
    *(f4v*)(out + i) = (f4v){0.f, 0.f, 0.f, 0.f};
}

// ---------------- zero per-call state ----------------
__global__ __launch_bounds__(256) void k_zero(int* __restrict__ ctrl, int* __restrict__ list,
                                              float* __restrict__ roww, float* __restrict__ out) {
    int id = blockIdx.x * 256 + threadIdx.x;
    *(f4v*)(out + (size_t)id * 4) = (f4v){0.f, 0.f, 0.f, 0.f};
    if (id < MAXROWS) { list[id] = 0; roww[id] = 0.f; }
    if (id < 64) ctrl[id] = 0;
}

// ---------------- transpose+cast (vectorized): f32 [R][C] -> bf16 [C][R] per expert ----------------
__global__ __launch_bounds__(256) void k_transpose(const float* __restrict__ in, u16* __restrict__ out,
                                                   int R, int C) {
    __shared__ float tile[64][65];
    size_t base = (size_t)blockIdx.z * R * C;
    const float* ip = in + base;
    u16* op = out + base;
    int c0 = blockIdx.x * 64, r0 = blockIdx.y * 64;
#pragma unroll
    for (int i = 0; i < 4; i++) {
        int idx = threadIdx.x + i * 256;
        int r = idx >> 4, c4 = (idx & 15) * 4;
        f4v v = *(const f4v*)(ip + (size_t)(r0 + r) * C + c0 + c4);
#pragma unroll
        for (int j = 0; j < 4; j++) tile[r][c4 + j] = v[j];
    }
    __syncthreads();
#pragma unroll
    for (int i = 0; i < 4; i++) {
        int idx = threadIdx.x + i * 256;
        int c = idx >> 4, r4 = (idx & 15) * 4;
        u16x4 o;
#pragma unroll
        for (int j = 0; j < 4; j++) o[j] = f2bf(tile[r4 + j][c]);
        *(u16x4*)(op + (size_t)(c0 + c) * R + r0 + r4) = o;
    }
}

// ---------------- gating (f32): softmax + top2, one wave/token; writes bf16 x copy; NO atomics ----------------
__global__ __launch_bounds__(256) void k_gate(const float* __restrict__ x, const float* __restrict__ Wg,
                                              const float* __restrict__ bg, float* __restrict__ comb,
                                              int* __restrict__ toke, u16* __restrict__ xbf) {
    int lane = threadIdx.x & 63;
    int t = (blockIdx.x * 4 + (threadIdx.x >> 6)) & (NTOK - 1);
    const float* xr = x + (size_t)t * HD;
    f4v xa = *(const f4v*)(xr + lane * 8);
    f4v xb = *(const f4v*)(xr + lane * 8 + 4);
    u16x8 o;
#pragma unroll
    for (int j = 0; j < 4; j++) { o[j] = f2bf(xa[j]); o[4 + j] = f2bf(xb[j]); }
    *(u16x8*)(xbf + (size_t)t * HD + lane * 8) = o;

    float p[8];
#pragma unroll
    for (int e = 0; e < 8; e++) p[e] = 0.f;
#pragma unroll
    for (int j = 0; j < 4; j++) {
        int h0 = lane * 8 + j, h1 = lane * 8 + 4 + j;
        f4v wa0 = *(const f4v*)(Wg + h0 * 8);
        f4v wa1 = *(const f4v*)(Wg + h0 * 8 + 4);
        f4v wb0 = *(const f4v*)(Wg + h1 * 8);
        f4v wb1 = *(const f4v*)(Wg + h1 * 8 + 4);
#pragma unroll
        for (int e = 0; e < 4; e++) {
            p[e]     += xa[j] * wa0[e] + xb[j] * wb0[e];
            p[4 + e] += xa[j] * wa1[e] + xb[j] * wb1[e];
        }
    }
#pragma unroll
    for (int off = 32; off > 0; off >>= 1)
#pragma unroll
        for (int e = 0; e < 8; e++) p[e] += __shfl_xor(p[e], off, 64);
#pragma unroll
    for (int e = 0; e < 8; e++) p[e] += bg[e];
    float mx = p[0];
#pragma unroll
    for (int e = 1; e < 8; e++) mx = fmaxf(mx, p[e]);
    float pr[8]; float s = 0.f;
#pragma unroll
    for (int e = 0; e < 8; e++) { pr[e] = __expf(p[e] - mx); s += pr[e]; }
    float inv = 1.f / s;
#pragma unroll
    for (int e = 0; e < 8; e++) pr[e] *= inv;
    int i1 = 0; float v1 = pr[0];
#pragma unroll
    for (int e = 1; e < 8; e++) if (pr[e] > v1) { v1 = pr[e]; i1 = e; }
    int i2 = 0; float v2 = -1.f;
#pragma unroll
    for (int e = 0; e < 8; e++) if (e != i1 && pr[e] > v2) { v2 = pr[e]; i2 = e; }
    if (lane == 0) {
#pragma unroll
        for (int e = 0; e < 8; e++) comb[t * 8 + e] = (e == i1 || e == i2) ? pr[e] : 0.f;
        toke[t] = i1 | (i2 << 8);
    }
}

// ---------------- counts via LDS aggregation ----------------
__global__ __launch_bounds__(1024) void k_count(const int* __restrict__ toke, int* __restrict__ ctrl) {
    __shared__ int sCnt[8];
    if (threadIdx.x < 8) sCnt[threadIdx.x] = 0;
    __syncthreads();
    int t = blockIdx.x * 1024 + threadIdx.x;
    int te = toke[t];
    atomicAdd(&sCnt[te & 7], 1);
    atomicAdd(&sCnt[(te >> 8) & 7], 1);
    __syncthreads();
    if (threadIdx.x < 8) atomicAdd(&ctrl[threadIdx.x], sCnt[threadIdx.x]);
}

// ---------------- plan: padded segment offsets + tile map (parallel fill) ----------------
__global__ __launch_bounds__(640) void k_plan(int* __restrict__ ctrl) {
    __shared__ int sOff[9], sSeg[9];
    if (threadIdx.x == 0) {
        int seg = 0, tt = 0;
        for (int e = 0; e < 8; e++) {
            sSeg[e] = seg; sOff[e] = tt;
            ctrl[16 + e] = seg;
            int nt = (ctrl[e] + 63) >> 6;
            tt += nt; seg += nt * 64;
        }
        sOff[8] = tt; sSeg[8] = seg;
        ctrl[24] = seg;
        ctrl[25] = (tt < MAXTILES) ? tt : MAXTILES;
    }
    __syncthreads();
    int ntile = sOff[8] < MAXTILES ? sOff[8] : MAXTILES;
    for (int tt = threadIdx.x; tt < ntile; tt += 640) {
        int e = 0;
        while (e < 7 && tt >= sOff[e + 1]) e++;
        int i = tt - sOff[e];
        ctrl[32 + tt * 3]     = e;
        ctrl[32 + tt * 3 + 1] = sSeg[e] + i * 64;
        ctrl[32 + tt * 3 + 2] = i * 64;
    }
}

// ---------------- scatter with LDS rank aggregation ----------------
__global__ __launch_bounds__(1024) void k_scatter(const int* __restrict__ toke, const float* __restrict__ comb,
                                                  int* __restrict__ ctrl, int* __restrict__ list,
                                                  float* __restrict__ roww) {
    __shared__ int sCnt[8], sBase[8];
    if (threadIdx.x < 8) sCnt[threadIdx.x] = 0;
    __syncthreads();
    int t = blockIdx.x * 1024 + threadIdx.x;
    int te = toke[t];
    int e1 = te & 7, e2 = (te >> 8) & 7;
    int r1 = atomicAdd(&sCnt[e1], 1);
    int r2 = atomicAdd(&sCnt[e2], 1);
    __syncthreads();
    if (threadIdx.x < 8) sBase[threadIdx.x] = atomicAdd(&ctrl[8 + threadIdx.x], sCnt[threadIdx.x]);
    __syncthreads();
    int g1 = min(ctrl[16 + e1] + sBase[e1] + r1, MAXROWS - 1);
    list[g1] = t; roww[g1] = comb[t * 8 + e1];
    int g2 = min(ctrl[16 + e2] + sBase[e2] + r2, MAXROWS - 1);
    list[g2] = t; roww[g2] = comb[t * 8 + e2];
}

// ---------------- fused expert FFN v5: R0 structure + async gload_lds staging, split barriers ----------------
// Staging via global_load_lds (width 16, zero staging VGPRs), XOR swizzles applied on the
// GLOBAL source address (involution) so LDS dest stays linear (m173 pattern).
// Pipeline per chunk: sW2(c+1) flies under phase1(c+1); sW1(c+1) flies under phase2(c).
// Raw s_barrier + counted vmcnt keeps loads in flight across barriers (T4).
__global__ __launch_bounds__(512, 4) void k_main(const u16* __restrict__ xbf, const float* __restrict__ b1g,
                                                 const float* __restrict__ b2g, const u16* __restrict__ W1T,
                                                 const u16* __restrict__ W2T, const int* __restrict__ ctrl,
                                                 int* __restrict__ steal, const int* __restrict__ list,
                                                 const float* __restrict__ roww, float* __restrict__ out) {
    __shared__ u16 sW1[32 * 512];   // logical [f][col], phys col granule = (c&~7)|((c&7)^(f&7))
    __shared__ u16 sW2[512 * 32];   // logical [n][cu*8], phys granule = cu^((n>>2)&3)
    __shared__ u16 sH[64 * 40];
    __shared__ int sTile;
    const int tid = threadIdx.x, wave = tid >> 6, lane = tid & 63;
    const int quad = lane >> 4, l15 = lane & 15;
    const int m4 = wave & 3, f2 = wave >> 2;       // phase-1 fragment assignment
    const int fs = f2 * 16 + l15;                  // f-row within chunk [0,32)
    const int total = min(ctrl[25], MAXTILES);

    // loop-invariant staging geometry
    const int w2n  = ((wave * 64 + lane) >> 2);            // n row for t8=0 (adds t8*128)
    const int w2cu = lane & 3;

    for (;;) {
        if (tid == 0) sTile = atomicAdd(steal, 1);
        __syncthreads();
        int bt = sTile;
        if (bt >= total) break;
        int e      = ctrl[32 + bt * 3] & 7;
        int row0   = min(ctrl[32 + bt * 3 + 1], MAXROWS - 64);
        int inseg0 = ctrl[32 + bt * 3 + 2];
        int cnt    = ctrl[e];
        const u16* w1e = W1T + (size_t)e * FD * HD;   // [f][h]
        const u16* w2e = W2T + (size_t)e * HD * FD;   // [n][f]
        const float* b1e = b1g + e * FD;

        int mA = m4 * 16 + l15;
        int tokA = (inseg0 + mA < cnt) ? (list[row0 + mA] & (NTOK - 1)) : 0;
        const u16* xrow = xbf + (size_t)tokA * HD + quad * 8;

        f4v Y[4][4];
#pragma unroll
        for (int mb = 0; mb < 4; mb++)
#pragma unroll
            for (int nb = 0; nb < 4; nb++) Y[mb][nb] = (f4v){0.f, 0.f, 0.f, 0.f};

        // ---- async stage issue helpers (macros keep size arg literal) ----
#define STAGE_W1(CC) {                                                              \
        const u16* wb = w1e + (size_t)(CC) * FCH * HD;                              \
        _Pragma("unroll")                                                           \
        for (int t8 = 0; t8 < 4; t8++) {                                            \
            int f = t8 * 8 + wave;                                                  \
            int g = (lane & ~7) | ((lane & 7) ^ (f & 7));                           \
            gload16(wb + (size_t)f * HD + g * 8, sW1 + f * 512);                    \
        } }
#define STAGE_W2(CC) {                                                              \
        const u16* wb = w2e + (size_t)(CC) * FCH;                                   \
        _Pragma("unroll")                                                           \
        for (int t8 = 0; t8 < 4; t8++) {                                            \
            int n = t8 * 128 + w2n;                                                 \
            int g = w2cu ^ ((n >> 2) & 3);                                          \
            gload16(wb + (size_t)n * FD + g * 8, sW2 + (t8 * 512 + wave * 64) * 8); \
        } }

        // prologue: stage chunk 0 (both buffers), full drain
        STAGE_W1(0);
        STAGE_W2(0);
        __syncthreads();

        for (int c = 0; c < NCH; c++) {
            // ---- phase 1: H[:,c] frag per wave (m4, f2), K=512; sW2(c) completes under this ----
            f4v h = (f4v){0.f, 0.f, 0.f, 0.f};
#pragma unroll
            for (int ks = 0; ks < 16; ks++) {
                s8v a = *(const s8v*)(xrow + ks * 32);
                int cidx = ks * 4 + quad;
                int phys = (cidx & ~7) | ((cidx & 7) ^ (fs & 7));
                s8v b = *(const s8v*)(sW1 + fs * 512 + phys * 8);
                h = mfma16(a, b, h);
            }
            float bb = b1e[c * FCH + fs];
#pragma unroll
            for (int r = 0; r < 4; r++)
                sH[(m4 * 16 + quad * 4 + r) * 40 + fs] = f2bf(gelu_f(h[r] + bb));
            asm volatile("s_waitcnt vmcnt(0) lgkmcnt(0)" ::: "memory");
            __builtin_amdgcn_s_barrier();                  // [C] sH + sW2(c) visible; sW1(c) dead
            __builtin_amdgcn_sched_barrier(0);
            if (c + 1 < NCH) STAGE_W1(c + 1);              // in flight during phase 2
            // ---- phase 2: Y += H_chunk @ W2_chunk; wave covers n in [wave*64, wave*64+64) ----
            s8v aH[4];
#pragma unroll
            for (int mb = 0; mb < 4; mb++)
                aH[mb] = *(const s8v*)(sH + (mb * 16 + l15) * 40 + quad * 8);
#pragma unroll
            for (int nb = 0; nb < 4; nb++) {
                int n = wave * 64 + nb * 16 + l15;
                s8v bw = *(const s8v*)(sW2 + n * 32 + ((quad ^ ((n >> 2) & 3)) * 8));
#pragma unroll
                for (int mb = 0; mb < 4; mb++) Y[mb][nb] = mfma16(aH[mb], bw, Y[mb][nb]);
            }
            asm volatile("s_waitcnt lgkmcnt(0)" ::: "memory");
            __builtin_amdgcn_s_barrier();                  // [A] sW2(c) + sH dead block-wide
            __builtin_amdgcn_sched_barrier(0);
            if (c + 1 < NCH) STAGE_W2(c + 1);              // in flight until next [C]
            asm volatile("s_waitcnt vmcnt(4)" ::: "memory");
            __builtin_amdgcn_s_barrier();                  // [B] sW1(c+1) visible (sW2 still out)
            __builtin_amdgcn_sched_barrier(0);
        }
        // ---- epilogue: (Y + b2) * routing weight, atomic accumulate into f32 out ----
        float b2v[4];
#pragma unroll
        for (int nb = 0; nb < 4; nb++) b2v[nb] = b2g[e * HD + wave * 64 + nb * 16 + l15];
#pragma unroll
        for (int mb = 0; mb < 4; mb++) {
#pragma unroll
            for (int r = 0; r < 4; r++) {
                int m = mb * 16 + quad * 4 + r;
                bool val = (inseg0 + m) < cnt;
                int tok = list[row0 + m] & (NTOK - 1);
                float wgt = val ? roww[row0 + m] : 0.f;
                float* orow = out + (size_t)tok * HD + wave * 64 + l15;
#pragma unroll
                for (int nb = 0; nb < 4; nb++)
                    atomicAdd(orow + nb * 16, (Y[mb][nb][r] + b2v[nb]) * wgt);
            }
        }
#undef STAGE_W1
#undef STAGE_W2
    }
}

extern "C" void kernel_launch(void* const* d_in, const int* in_sizes, int n_in,
                              void* d_out, int out_size, void* d_ws, size_t ws_size,
                              hipStream_t stream) {
    const float* x  = (const float*)d_in[0];
    const float* Wg = (const float*)d_in[1];
    const float* bg = (const float*)d_in[2];
    const float* W1 = (const float*)d_in[3];
    const float* b1 = (const float*)d_in[4];
    const float* W2 = (const float*)d_in[5];
    const float* b2 = (const float*)d_in[6];
    (void)in_sizes; (void)n_in; (void)out_size;
    float* out = (float*)d_out;

    if (ws_size < WS_NEED) {
        k_fallback<<<(NTOK * HD / 4) / 256, 256, 0, stream>>>(out);
        return;
    }

    char* ws = (char*)d_ws;
    int*   ctrl = (int*)(ws + CTRL_OFF);
    int*   toke = (int*)(ws + TOKE_OFF);
    float* comb = (float*)(ws + COMB_OFF);
    int*   list = (int*)(ws + LIST_OFF);
    float* roww = (float*)(ws + ROWW_OFF);
    u16*   xbf  = (u16*)(ws + XBF_OFF);
    u16*   w1t  = (u16*)(ws + W1T_OFF);
    u16*   w2t  = (u16*)(ws + W2T_OFF);

    k_zero<<<(NTOK * HD / 4) / 256, 256, 0, stream>>>(ctrl, list, roww, out);
    k_transpose<<<dim3(FD / 64, HD / 64, NE), dim3(256), 0, stream>>>(W1, w1t, HD, FD);
    k_transpose<<<dim3(HD / 64, FD / 64, NE), dim3(256), 0, stream>>>(W2, w2t, FD, HD);
    k_gate<<<NTOK / 4, 256, 0, stream>>>(x, Wg, bg, comb, toke, xbf);
    k_count<<<NTOK / 1024, 1024, 0, stream>>>(toke, ctrl);
    k_plan<<<1, 640, 0, stream>>>(ctrl);
    k_scatter<<<NTOK / 1024, 1024, 0, stream>>>(toke, comb, ctrl, list, roww);
    k_main<<<512, 512, 0, stream>>>(xbf, b1, b2, w1t, w2t, ctrl, ctrl + 26, list, roww, out);
}